// Round 11
// baseline (266.687 us; speedup 1.0000x reference)
//
#include <hip/hip_runtime.h>

typedef unsigned int u32;
typedef unsigned char u8;
typedef unsigned long long u64;
typedef int i32x4 __attribute__((ext_vector_type(4)));
typedef int i32x16 __attribute__((ext_vector_type(16)));

// Workspace layout (3.8 MB used):
//   [0, 589824)          Wm[step=tap*8+kc][oc][ic32] i8 (+/-1), 8KB per step
//   [589824, +3211264)   bp bitplanes: bp[(n*256+ch)*49 + (px>>6)], bit px&63
#define WM_OFF 0
#define BP_OFF 589824

// ---------------------------------------------------------------------------
// Kernel 1: prep = pack_w (blocks 0..2303) + bin_bits (blocks 2304..3871).
// ---------------------------------------------------------------------------
__global__ __launch_bounds__(256) void prep(const int* __restrict__ enc,
                                            const float* __restrict__ cb,
                                            char* __restrict__ wm,
                                            const float* __restrict__ x,
                                            u64* __restrict__ bp) {
    int bid = blockIdx.x;
    if (bid < 2304) {
        int idx  = bid * 256 + threadIdx.x;          // 0..589823
        int icin = idx & 31;
        int oc   = (idx >> 5) & 255;
        int step = idx >> 13;                        // 0..71 = tap*8+kc
        int tap  = step >> 3;
        int kc   = step & 7;
        int i = kc * 32 + icin;
        int f = oc * 2304 + i * 9 + tap;             // OIHW flat index
        int j = f / 12;
        int t = f - j * 12;
        float v = cb[enc[j] * 12 + t];
        wm[idx] = v < 0.f ? (char)-1 : (char)1;
    } else {
        int gw   = (bid - 2304) * 4 + (threadIdx.x >> 6);  // 0..6271
        int lane = threadIdx.x & 63;
        const float* xb = x + (size_t)gw * 4096 + lane;
#pragma unroll 1
        for (int k = 0; k < 8; ++k) {
            float v[8];
#pragma unroll
            for (int j = 0; j < 8; ++j) v[j] = xb[k * 512 + j * 64];
            u64 mine = 0;
#pragma unroll
            for (int j = 0; j < 8; ++j) {
                u64 m = __ballot(v[j] < 0.f);
                if (lane == j) mine = m;
            }
            if (lane < 8) bp[(size_t)gw * 64 + k * 8 + lane] = mine;
        }
    }
}

// ---------------------------------------------------------------------------
// Expand one padded row of bitplanes into the swizzled LDS X-tile.
// thread (oct, wseg): channels oct*8..+8, w' = wseg+4k. 16 bp loads (L2-hot),
// 15 u64 LDS writes at [wq*256 + (oct*8 ^ ((wq&15)<<4))].
// ---------------------------------------------------------------------------
__device__ __forceinline__ void expand_row(const u64* __restrict__ bp, u8* xr,
                                           int n, int h, int oct, int wseg) {
    bool rowv = (h >= 0) && (h <= 55);
    int w0c = rowv ? ((h * 56) >> 6) : 0;
    int w1c = w0c + 1; if (w1c > 48) w1c = 48;
    const u64* bq = bp + ((size_t)n * 256 + oct * 8) * 49;
    u64 A[8], B[8];
#pragma unroll
    for (int j = 0; j < 8; ++j) A[j] = bq[j * 49 + w0c];
#pragma unroll
    for (int j = 0; j < 8; ++j) B[j] = bq[j * 49 + w1c];
#pragma unroll 1
    for (int k = 0; k < 15; ++k) {
        int wq = wseg + k * 4;
        if (wq >= 58) break;
        u64 out = 0;
        if (rowv && wq >= 1 && wq <= 56) {
            int px  = h * 56 + wq - 1;
            int bit = px & 63;
            bool s2 = (px >> 6) != w0c;
#pragma unroll
            for (int j = 0; j < 8; ++j) {
                u64 wv = s2 ? B[j] : A[j];
                out |= (((wv >> bit) & 1ull) ? 0xFFull : 0x01ull) << (8 * j);
            }
        }
        *(u64*)(xr + wq * 256 + ((oct * 8) ^ ((wq & 15) << 4))) = out;
    }
}

// ---------------------------------------------------------------------------
// Kernel 2: i8 MFMA conv (R11 = R10 + per-wave s_sleep skew, single-variable).
// R10 post-mortem: MFMA 30% + VALU 26% + LDS 21% + L1 ~27% and dur == SUM of
// pipe times -> pipes never co-run. Cause theory: all 16 waves/CU leave the
// barrier in instruction lockstep (identical code+latencies) -> every pipe
// bursts in sync then idles. Fix under test: one-time per-wave s_sleep
// (64*w cyc, w=0..7; step round ~586 cyc) to phase-shift the waves; the
// barrier-free K-loop preserves the skew. Everything else IDENTICAL to R10.
// Prediction: conv 96 -> 65-80us, MfmaUtil 30 -> 40-48 if theory holds;
// null (+-3us) falsifies -> next lever is LDS-staged double-buffered A.
// C/D: col=l&31 (px), row=(q&3)+8*(q>>2)+4*(l>>5) (oc)  [HW-verified].
// ---------------------------------------------------------------------------
__global__ __launch_bounds__(512, 4) void conv_mfma(const u64* __restrict__ bp,
                                                    const char* __restrict__ wm,
                                                    float* __restrict__ y) {
    __shared__ __align__(16) u8 xl[61952];   // 4*14848 + dead-prefetch slack
    int t = threadIdx.x;
    // XCD-aware bijective remap (896 % 8 == 0): 4 consecutive n per XCD.
    int lin = blockIdx.x + 28 * blockIdx.y;
    int swb = (lin & 7) * 112 + (lin >> 3);
    int n   = swb / 28;
    int h0  = (swb - n * 28) * 2;

    int oct = t & 31, wseg = (t >> 5) & 3, rr = t >> 7;
    int wave = t >> 6, lane = t & 63;
    int ocg  = wave & 3;
    int pxg  = wave >> 2;
    int col  = lane & 31;
    int half = lane >> 5;
    int ocw  = ocg * 64;
    int aoff = (ocw + col) * 32 + half * 16;
    int h16  = half * 16;

    // Prime A even-slot with step 0 (global, no LDS dep -> hides under the
    // expansion + barrier).
    const char* wb = wm;
    i32x4 Aea = *(const i32x4*)(wb + aoff);
    i32x4 Aeb = *(const i32x4*)(wb + aoff + 1024);
    wb += 8192;                               // -> step 1

    expand_row(bp, xl + rr * 14848, n, h0 + rr - 1, oct, wseg);
    __syncthreads();

    // R11: temporal skew. Wave w sleeps ~64*w cycles ONCE; with identical
    // downstream instruction streams the phase offset persists, so the 4
    // waves/SIMD stop bursting the same pipe simultaneously.
    switch (wave) {
        case 1: __builtin_amdgcn_s_sleep(1); break;
        case 2: __builtin_amdgcn_s_sleep(2); break;
        case 3: __builtin_amdgcn_s_sleep(3); break;
        case 4: __builtin_amdgcn_s_sleep(4); break;
        case 5: __builtin_amdgcn_s_sleep(5); break;
        case 6: __builtin_amdgcn_s_sleep(6); break;
        case 7: __builtin_amdgcn_s_sleep(7); break;
        default: break;
    }

    int swA = ((col + 0) & 15) << 4, cbA = (col + 0) * 256;
    int swB = ((col + 1) & 15) << 4, cbB = (col + 1) * 256;
    int swC = ((col + 2) & 15) << 4, cbC = (col + 2) * 256;
    int pxb = pxg * 14848;

    i32x16 acc[2][2] = {};
    i32x4 Aoa, Aob, Be0, Be1, Bo0, Bo1;

#define MFMA4(AA, AB, B0, B1)                                                  \
    acc[0][0] = __builtin_amdgcn_mfma_i32_32x32x32_i8(AA, B0, acc[0][0], 0, 0, 0); \
    acc[0][1] = __builtin_amdgcn_mfma_i32_32x32x32_i8(AA, B1, acc[0][1], 0, 0, 0); \
    acc[1][0] = __builtin_amdgcn_mfma_i32_32x32x32_i8(AB, B0, acc[1][0], 0, 0, 0); \
    acc[1][1] = __builtin_amdgcn_mfma_i32_32x32x32_i8(AB, B1, acc[1][1], 0, 0, 0);

// One region = one (r,s) tap: 8 K-steps as 4 unroll-1 iterations of 2 steps.
// Loop-carried Ae/Be live in fixed regs (no movs); prefetches sit one full
// MFMA4 ahead of their consumer. kc2=3's Be prefetch is dead (in-bounds).
#define REGION(CBASE, SWV)                                                     \
    {                                                                          \
        const int _bb = (CBASE);                                               \
        {                                                                      \
            int _p = _bb + (h16 ^ (SWV));                                      \
            Be0 = *(const i32x4*)&xl[_p];                                      \
            Be1 = *(const i32x4*)&xl[_p + 8192];                               \
        }                                                                      \
        _Pragma("unroll 1")                                                    \
        for (int kc2 = 0; kc2 < 4; ++kc2) {                                    \
            int _kb = kc2 * 64;                                                \
            int _ko = _bb + ((_kb + 32 + h16) ^ (SWV));                        \
            Bo0 = *(const i32x4*)&xl[_ko];                                     \
            Bo1 = *(const i32x4*)&xl[_ko + 8192];                              \
            Aoa = *(const i32x4*)(wb + aoff);                                  \
            Aob = *(const i32x4*)(wb + aoff + 1024);                           \
            wb += 8192;                                                        \
            MFMA4(Aea, Aeb, Be0, Be1)                                          \
            int _ke = _bb + ((_kb + 64 + h16) ^ (SWV));                        \
            Be0 = *(const i32x4*)&xl[_ke];                                     \
            Be1 = *(const i32x4*)&xl[_ke + 8192];                              \
            Aea = *(const i32x4*)(wb + aoff);                                  \
            Aeb = *(const i32x4*)(wb + aoff + 1024);                           \
            wb += 8192;                                                        \
            MFMA4(Aoa, Aob, Bo0, Bo1)                                          \
        }                                                                      \
    }

#pragma unroll 1
    for (int r = 0; r < 3; ++r) {
        int rowb = pxb + r * 14848;
        REGION(rowb + cbA, swA)
        REGION(rowb + cbB, swB)
        REGION(rowb + cbC, swC)
    }
#undef REGION
#undef MFMA4

    // Final Ae prefetch walked to step 72 (8KB into bp region): dead, valid.
    int h = h0 + pxg;
    float* yb = y + (size_t)n * 256 * 3136 + (size_t)h * 56;
#pragma unroll
    for (int at = 0; at < 2; ++at) {
#pragma unroll
        for (int bt = 0; bt < 2; ++bt) {
            int w = bt * 32 + col;
            if (w < 56) {
#pragma unroll
                for (int q = 0; q < 16; ++q) {
                    int oc = ocw + at * 32 + (q & 3) + 8 * (q >> 2) + 4 * half;
                    yb[(size_t)oc * 3136 + w] = (float)acc[at][bt][q];
                }
            }
        }
    }
}

extern "C" void kernel_launch(void* const* d_in, const int* in_sizes, int n_in,
                              void* d_out, int out_size, void* d_ws, size_t ws_size,
                              hipStream_t stream) {
    const float* x  = (const float*)d_in[0];
    // d_in[1] (latent weight) unused in the STE forward value.
    const float* cb = (const float*)d_in[2];
    const int* enc  = (const int*)d_in[3];
    float* y        = (float*)d_out;

    char* wmc = (char*)d_ws + WM_OFF;
    u64*  bp  = (u64*)((char*)d_ws + BP_OFF);

    hipLaunchKernelGGL(prep, dim3(3872), dim3(256), 0, stream, enc, cb, wmc, x, bp);
    hipLaunchKernelGGL(conv_mfma, dim3(28, 32), dim3(512), 0, stream, bp, wmc, y);
}